// Round 15
// baseline (1638.504 us; speedup 1.0000x reference)
//
#include <hip/hip_runtime.h>
#include <math.h>

// MambaBlock: B=8, T=2048, D_MODEL=1024, D_STATE=256.
// R15: R14 exactly, with ONE isolated change: scan step MFMA accumulation
// restructured from 2 chains x depth 4 to 4 chains x depth 2 (per m-tile),
// to take dependent-MFMA latency off the step critical path.

enum { E_NONE = 0, E_BIASBF = 1, E_SIGBF = 2, E_GATE = 3, E_BIASRES = 4,
       E_CVTBF = 5, E_BIASF32 = 6 };

typedef __attribute__((ext_vector_type(8))) short bf16x8;
typedef __attribute__((ext_vector_type(4))) float f32x4;

static __device__ inline unsigned short f2bf(float f) {
    unsigned u = __builtin_bit_cast(unsigned, f);
    unsigned r = (u + 0x7fff + ((u >> 16) & 1)) >> 16;
    return (unsigned short)r;
}
static __device__ inline unsigned pack2(float a, float b) {
    return (unsigned)f2bf(a) | ((unsigned)f2bf(b) << 16);
}
static __device__ inline float bflo(unsigned u) {
    return __builtin_bit_cast(float, u << 16);
}
static __device__ inline float bfhi(unsigned u) {
    return __builtin_bit_cast(float, u & 0xffff0000u);
}
static __device__ inline float tanh_fast(float x) {
    float e = __builtin_amdgcn_exp2f(x * 2.8853900817779268f);
    float t = __builtin_amdgcn_rcpf(e + 1.0f);
    return fmaf(-2.0f, t, 1.0f);
}

// ---------------- flag helpers (device-scope release/acquire) ----------------
static __device__ __forceinline__ void wait_ge(unsigned* p, unsigned tgt, int tid) {
    if (tid == 0) {
        while (atomicAdd(p, 0u) < tgt) __builtin_amdgcn_s_sleep(2);
        __threadfence();   // acquire
    }
    __syncthreads();
}

// ---------------- role bodies ----------------
static __device__ __forceinline__ void cvt_body(
    const float* __restrict__ in, unsigned short* __restrict__ out, int i, int n8)
{
    if (i >= n8) return;
    float4 a = ((const float4*)in)[i * 2];
    float4 b = ((const float4*)in)[i * 2 + 1];
    uint4 o;
    o.x = pack2(a.x, a.y); o.y = pack2(a.z, a.w);
    o.z = pack2(b.x, b.y); o.w = pack2(b.z, b.w);
    ((uint4*)out)[i] = o;
}

static __device__ __forceinline__ void transpose_tile(
    bool act, unsigned char* LdsB, int bxi, int byi, int t2,
    const float* __restrict__ in, unsigned short* __restrict__ out, int R, int C)
{
    float* tile = (float*)LdsB;  // [32][33]
    const int bx = bxi * 32, by = byi * 32;
    const int tx = t2 & 31, ty = t2 >> 5;  // ty 0..7
    if (act) {
#pragma unroll
        for (int i = 0; i < 32; i += 8)
            tile[(ty + i) * 33 + tx] = in[(size_t)(by + ty + i) * C + bx + tx];
    }
    __syncthreads();
    if (act) {
#pragma unroll
        for (int i = 0; i < 32; i += 8)
            out[(size_t)(bx + ty + i) * R + by + tx] = f2bf(tile[tx * 33 + ty + i]);
    }
}

// ---------------- combined prepass (role blocks) ----------------
__global__ __launch_bounds__(256) void prep_all(
    const float* __restrict__ x, unsigned short* __restrict__ xbf,
    const float* __restrict__ W_in, unsigned short* __restrict__ Winbf,
    const float* __restrict__ Dm, unsigned short* __restrict__ Dbf,
    const float* __restrict__ Bm, unsigned short* __restrict__ BmT,
    const float* __restrict__ W_gate, unsigned short* __restrict__ WgT,
    const float* __restrict__ W_out, unsigned short* __restrict__ WoT,
    const float* __restrict__ Cm, unsigned short* __restrict__ Cbf,
    const float* __restrict__ b_in, float* __restrict__ b2, float* __restrict__ bD)
{
    __shared__ __align__(16) unsigned char Lds[32 * 33 * 4];
    const unsigned bid = blockIdx.x;
    const int tid = threadIdx.x;
    if (bid < 8192) {
        cvt_body(x, xbf, bid * 256 + tid, 16384 * 1024 / 8);
    } else if (bid < 8320) {
        cvt_body(W_in, Winbf, (bid - 8192) * 256 + tid, 1024 * 256 / 8);
    } else if (bid < 8448) {
        cvt_body(Dm, Dbf, (bid - 8320) * 256 + tid, 1024 * 256 / 8);
    } else if (bid < 8512) {
        const int t = bid - 8448;
        transpose_tile(true, Lds, t & 7, t >> 3, tid, Bm, BmT, 256, 256);
    } else if (bid < 9536) {
        const int t = bid - 8512;
        transpose_tile(true, Lds, t & 31, t >> 5, tid, W_gate, WgT, 1024, 1024);
    } else if (bid < 10560) {
        const int t = bid - 9536;
        transpose_tile(true, Lds, t & 31, t >> 5, tid, W_out, WoT, 1024, 1024);
    } else if (bid < 10688) {
        cvt_body(Cm, Cbf, (bid - 10560) * 256 + tid, 1024 * 256 / 8);
    } else if (bid == 10688) {
        float s = 0.f;
        for (int k = 0; k < 256; ++k) s = fmaf(b_in[k], Bm[k * 256 + tid], s);
        b2[tid] = s;
    } else {
        const int n = (bid - 10689) * 256 + tid;
        float s = 0.f;
        for (int k = 0; k < 256; ++k) s = fmaf(b_in[k], Dm[n * 256 + k], s);
        bD[n] = s;
    }
}

// ---------------- bf16 MFMA GEMM tile: C[M,N] = A[M,K] * B[N,K]^T ----------
template <int EPI>
static __device__ __forceinline__ void gemm_tile(
    bool act, unsigned char* Lds, int bx, int by, int tid,
    const unsigned short* __restrict__ Ag,  // [M,K] bf16
    const unsigned short* __restrict__ Bg,  // [N,K] bf16
    const float* __restrict__ bias, const float* __restrict__ res,
    const float* __restrict__ acc_src, const unsigned short* __restrict__ g8,
    void* Cg, int M, int N, int K)
{
    const int w = (tid >> 6) & 3, l = tid & 63;
    const int r = l & 15, g = l >> 4;
    const int m0 = by * 128, n0 = bx * 128;

    const unsigned char* agp[4];
    const unsigned char* bgp[4];
#pragma unroll
    for (int j = 0; j < 4; ++j) {
        const int c = w * 256 + j * 64 + l;
        const int row = c >> 3;
        const unsigned offp = ((unsigned)(c & 7) * 16u) ^ ((unsigned)(row & 7) * 16u);
        agp[j] = (const unsigned char*)Ag + ((size_t)(m0 + row) * K) * 2 + offp;
        bgp[j] = (const unsigned char*)Bg + ((size_t)(n0 + row) * K) * 2 + offp;
    }

#define GSTAGE(BUF)                                                           \
    {                                                                         \
      _Pragma("unroll")                                                       \
      for (int j = 0; j < 4; ++j) {                                           \
        __builtin_amdgcn_global_load_lds(                                     \
            (const __attribute__((address_space(1))) unsigned*)(agp[j]),      \
            (__attribute__((address_space(3))) unsigned*)(Lds + (BUF) * 32768 + w * 4096 + j * 1024), \
            16, 0, 0);                                                        \
        __builtin_amdgcn_global_load_lds(                                     \
            (const __attribute__((address_space(1))) unsigned*)(bgp[j]),      \
            (__attribute__((address_space(3))) unsigned*)(Lds + (BUF) * 32768 + 16384 + w * 4096 + j * 1024), \
            16, 0, 0);                                                        \
        agp[j] += 128; bgp[j] += 128;                                         \
      }                                                                       \
    }

    f32x4 acc[2][8];
#pragma unroll
    for (int mt = 0; mt < 2; ++mt)
#pragma unroll
        for (int nt = 0; nt < 8; ++nt) acc[mt][nt] = (f32x4){0.f, 0.f, 0.f, 0.f};

    const int nk = K >> 6;
    if (act) GSTAGE(0)
    __syncthreads();
    for (int t = 0; t < nk; ++t) {
        const int buf = t & 1;
        if (act) {
            if (t + 1 < nk) GSTAGE(buf ^ 1)
            bf16x8 af[2][2], bfr[8][2];
#pragma unroll
            for (int s = 0; s < 2; ++s) {
#pragma unroll
                for (int mt = 0; mt < 2; ++mt) {
                    const int row = w * 32 + mt * 16 + r;
                    af[mt][s] = *(const bf16x8*)(Lds + buf * 32768 + row * 128 +
                        ((s * 64 + 16 * g) ^ (16 * (row & 7))));
                }
#pragma unroll
                for (int nt = 0; nt < 8; ++nt) {
                    const int row = nt * 16 + r;
                    bfr[nt][s] = *(const bf16x8*)(Lds + buf * 32768 + 16384 + row * 128 +
                        ((s * 64 + 16 * g) ^ (16 * (row & 7))));
                }
            }
#pragma unroll
            for (int s = 0; s < 2; ++s)
#pragma unroll
                for (int mt = 0; mt < 2; ++mt)
#pragma unroll
                    for (int nt = 0; nt < 8; ++nt)
                        acc[mt][nt] = __builtin_amdgcn_mfma_f32_16x16x32_bf16(
                            af[mt][s], bfr[nt][s], acc[mt][nt], 0, 0, 0);
        }
        __syncthreads();
    }
#undef GSTAGE

    if (act) {
#pragma unroll
        for (int mt = 0; mt < 2; ++mt)
#pragma unroll
            for (int nt = 0; nt < 8; ++nt) {
                const int n = n0 + nt * 16 + r;
                float bv = 0.f;
                if (EPI == E_BIASBF || EPI == E_SIGBF || EPI == E_BIASRES ||
                    EPI == E_BIASF32) bv = bias[n];
#pragma unroll
                for (int q = 0; q < 4; ++q) {
                    const int m = m0 + w * 32 + mt * 16 + g * 4 + q;
                    const size_t idx = (size_t)m * N + n;
                    float v = acc[mt][nt][q] + bv;
                    if (EPI == E_SIGBF) v = 1.f / (1.f + expf(-v));
                    if (EPI == E_BIASRES) v += res[idx];
                    if (EPI == E_GATE) {
                        v += acc_src[idx];
                        const float gg = bflo((unsigned)g8[idx]);
                        v = gg * v + (1.f - gg) * res[idx];
                    }
                    if (EPI == E_BIASBF || EPI == E_SIGBF || EPI == E_CVTBF ||
                        EPI == E_GATE)
                        ((unsigned short*)Cg)[idx] = f2bf(v);
                    else
                        ((float*)Cg)[idx] = v;
                }
            }
    }
}

template <int EPI>
__global__ __launch_bounds__(256) void gemm_mfma(
    const unsigned short* __restrict__ Ag, const unsigned short* __restrict__ Bg,
    const float* __restrict__ bias, const float* __restrict__ res,
    const float* __restrict__ acc_src, const unsigned short* __restrict__ g8,
    void* Cg, int M, int N, int K)
{
    __shared__ __align__(16) unsigned char Lds[65536];
    gemm_tile<EPI>(true, Lds, blockIdx.x, blockIdx.y, threadIdx.x,
                   Ag, Bg, bias, res, acc_src, g8, Cg, M, N, K);
}

// ---------------- 8-wave MFMA scan body (R15: 4 chains x depth 2) ----------
static __device__ __forceinline__ void scan_body(
    unsigned char* LDSM, int tid,
    const float* __restrict__ Amat, const unsigned short* __restrict__ u2bf,
    unsigned short* __restrict__ hbf, unsigned* __restrict__ scan_prog)
{
    constexpr int T = 2048;
    constexpr int NCH = T / 8;  // 256 chunks
    unsigned char* Hb = LDSM;              // ring [16][4096]
    unsigned char* Ub = LDSM + 65536;      // [2 buf][8 steps][8 b][512 B]

    const int w = tid >> 6, l = tid & 63;
    const int r = l & 15, g = l >> 4, r8 = r & 7;
    const bool hi = (r & 8) != 0;
    const int m0 = w * 32;

    ((unsigned*)Hb)[tid] = 0u;
    ((unsigned*)Hb)[tid + 512] = 0u;

    bf16x8 af[2][8];
#pragma unroll
    for (int mt = 0; mt < 2; ++mt) {
        const int m = m0 + mt * 16 + r;
#pragma unroll
        for (int kt = 0; kt < 8; ++kt) {
            unsigned wd[4];
#pragma unroll
            for (int jw = 0; jw < 4; ++jw) {
                const int k = kt * 32 + g * 8 + jw * 2;
                wd[jw] = pack2(Amat[(size_t)k * 256 + m],
                               Amat[(size_t)(k + 1) * 256 + m]);
            }
            af[mt][kt] = __builtin_bit_cast(bf16x8, *(uint4*)wd);
        }
    }

    unsigned ubase[2], woff[2];
#pragma unroll
    for (int mt = 0; mt < 2; ++mt) {
        const int s0 = m0 + mt * 16 + g * 4;
        const int s = s0 + (hi ? 2 : 0);
        ubase[mt] = (unsigned)(r8 * 512 + (((s >> 3) ^ r8) * 16) + (s & 7) * 2);
        woff[mt] = (unsigned)((((s0 >> 5) * 32 + ((s0 >> 3) & 3) * 8 + r8) * 16)
                              + ((s0 & 7) + (hi ? 2 : 0)) * 2);
    }
    const unsigned rbase = (unsigned)((g * 8 + r8) * 16);

    int sg_i[4], sg_b[4], sg_kg[4];
#pragma unroll
    for (int j = 0; j < 4; ++j) {
        const int d = j * 512 + tid;
        sg_i[j] = d >> 8;
        sg_b[j] = (d >> 5) & 7;
        sg_kg[j] = (d & 31) ^ sg_b[j];
    }

#pragma unroll
    for (int c0 = 0; c0 < 2; ++c0)
#pragma unroll
        for (int j = 0; j < 4; ++j) {
            const size_t srcb = ((size_t)(sg_b[j] * T + c0 * 8 + sg_i[j]) * 512)
                              + (unsigned)(sg_kg[j] * 16);
            __builtin_amdgcn_global_load_lds(
                (const __attribute__((address_space(1))) unsigned*)(
                    (const unsigned char*)u2bf + srcb),
                (__attribute__((address_space(3))) unsigned*)(
                    Ub + c0 * 32768 + (j * 512 + tid) * 16), 16, 0, 0);
        }
    asm volatile("s_waitcnt vmcnt(0) lgkmcnt(0)" ::: "memory");
    __builtin_amdgcn_sched_barrier(0);
    __builtin_amdgcn_s_barrier();
    __builtin_amdgcn_sched_barrier(0);

#define SCAN_STEP(I)                                                          \
  {                                                                           \
    const unsigned sr = ((unsigned)(t0 + (I)) & 15u) * 4096u;                 \
    const unsigned sw = ((unsigned)(t0 + (I) + 1) & 15u) * 4096u;             \
    bf16x8 hf[8];                                                             \
    _Pragma("unroll")                                                         \
    for (int kt = 0; kt < 8; ++kt)                                            \
      hf[kt] = *(const bf16x8*)(Hb + sr + rbase + (unsigned)(kt * 512));      \
    unsigned uv[2];                                                           \
    _Pragma("unroll")                                                         \
    for (int mt = 0; mt < 2; ++mt)                                            \
      uv[mt] = *(const unsigned*)(Uc + (unsigned)(I) * 4096u + ubase[mt]);    \
    f32x4 c0[2], c1[2], c2[2], c3[2];                                         \
    _Pragma("unroll")                                                         \
    for (int mt = 0; mt < 2; ++mt) {                                          \
      c0[mt] = (f32x4){0.f, 0.f, 0.f, 0.f};                                   \
      c1[mt] = (f32x4){0.f, 0.f, 0.f, 0.f};                                   \
      c2[mt] = (f32x4){0.f, 0.f, 0.f, 0.f};                                   \
      c3[mt] = (f32x4){0.f, 0.f, 0.f, 0.f};                                   \
    }                                                                         \
    /* round 1: 8 independent MFMAs */                                        \
    _Pragma("unroll")                                                         \
    for (int mt = 0; mt < 2; ++mt) {                                          \
      c0[mt] = __builtin_amdgcn_mfma_f32_16x16x32_bf16(af[mt][0], hf[0],      \
                                                       c0[mt], 0, 0, 0);      \
      c1[mt] = __builtin_amdgcn_mfma_f32_16x16x32_bf16(af[mt][2], hf[2],      \
                                                       c1[mt], 0, 0, 0);      \
      c2[mt] = __builtin_amdgcn_mfma_f32_16x16x32_bf16(af[mt][4], hf[4],      \
                                                       c2[mt], 0, 0, 0);      \
      c3[mt] = __builtin_amdgcn_mfma_f32_16x16x32_bf16(af[mt][6], hf[6],      \
                                                       c3[mt], 0, 0, 0);      \
    }                                                                         \
    /* round 2: 8 dependent MFMAs (depth 2 total) */                          \
    _Pragma("unroll")                                                         \
    for (int mt = 0; mt < 2; ++mt) {                                          \
      c0[mt] = __builtin_amdgcn_mfma_f32_16x16x32_bf16(af[mt][1], hf[1],      \
                                                       c0[mt], 0, 0, 0);      \
      c1[mt] = __builtin_amdgcn_mfma_f32_16x16x32_bf16(af[mt][3], hf[3],      \
                                                       c1[mt], 0, 0, 0);      \
      c2[mt] = __builtin_amdgcn_mfma_f32_16x16x32_bf16(af[mt][5], hf[5],      \
                                                       c2[mt], 0, 0, 0);      \
      c3[mt] = __builtin_amdgcn_mfma_f32_16x16x32_bf16(af[mt][7], hf[7],      \
                                                       c3[mt], 0, 0, 0);      \
    }                                                                         \
    _Pragma("unroll")                                                         \
    for (int mt = 0; mt < 2; ++mt) {                                          \
      const int q0 = hi ? 2 : 0;                                              \
      const float slo = (c0[mt][q0] + c1[mt][q0]) +                           \
                        (c2[mt][q0] + c3[mt][q0]);                            \
      const float shi = (c0[mt][q0 + 1] + c1[mt][q0 + 1]) +                   \
                        (c2[mt][q0 + 1] + c3[mt][q0 + 1]);                    \
      const float h0 = tanh_fast(slo + bflo(uv[mt]));                         \
      const float h1 = tanh_fast(shi + bfhi(uv[mt]));                         \
      unsigned pk;                                                            \
      asm("v_cvt_pk_bf16_f32 %0, %1, %2" : "=v"(pk) : "v"(h0), "v"(h1));      \
      *(unsigned*)(Hb + sw + woff[mt]) = pk;                                  \
    }                                                                         \
    asm volatile("s_waitcnt lgkmcnt(0)" ::: "memory");                        \
    __builtin_amdgcn_sched_barrier(0);                                        \
    __builtin_amdgcn_s_barrier();                                             \
    __builtin_amdgcn_sched_barrier(0);                                        \
  }

    for (int chunk = 0; chunk < NCH; ++chunk) {
        const int t0 = chunk * 8;
        const unsigned char* Uc = Ub + ((unsigned)(chunk & 1) << 15);

        SCAN_STEP(0)
        SCAN_STEP(1)
        SCAN_STEP(2)
        SCAN_STEP(3)
        SCAN_STEP(4)
        SCAN_STEP(5)
        SCAN_STEP(6)
        SCAN_STEP(7)

        {
#pragma unroll
            for (int j = 0; j < 4; ++j) {
                const int p = j * 512 + tid;
                const int di = p >> 8, wp = p & 255;
                const int kt_ = wp >> 5, sl_ = wp & 31;
                const unsigned slot = (unsigned)((t0 + 1 + di) & 15) * 4096u;
                uint4 dat = *(const uint4*)(Hb + slot + (unsigned)wp * 16u);
                const size_t off = ((size_t)((sl_ & 7) * T + t0 + di) * 256 +
                                    kt_ * 32 + (sl_ >> 3) * 8);
                *(uint4*)(hbf + off) = dat;
            }
            if (chunk + 2 < NCH) {
                const unsigned nb = (unsigned)(chunk & 1) << 15;
#pragma unroll
                for (int j = 0; j < 4; ++j) {
                    const size_t srcb =
                        ((size_t)(sg_b[j] * T + t0 + 16 + sg_i[j]) * 512)
                        + (unsigned)(sg_kg[j] * 16);
                    __builtin_amdgcn_global_load_lds(
                        (const __attribute__((address_space(1))) unsigned*)(
                            (const unsigned char*)u2bf + srcb),
                        (__attribute__((address_space(3))) unsigned*)(
                            Ub + nb + (j * 512 + tid) * 16), 16, 0, 0);
                }
                asm volatile("s_waitcnt vmcnt(8) lgkmcnt(0)" ::: "memory");
            } else {
                asm volatile("s_waitcnt vmcnt(0) lgkmcnt(0)" ::: "memory");
            }
            __builtin_amdgcn_sched_barrier(0);
            __builtin_amdgcn_s_barrier();
            __builtin_amdgcn_sched_barrier(0);
            if ((chunk & 15) == 15 && tid == 0) {
                __threadfence();
                atomicAdd(scan_prog, 1u);
            }
        }
    }
#undef SCAN_STEP
}

// ---------------- fused kernel ----------------
__global__ __launch_bounds__(512, 1) void fused_scan(
    const float* __restrict__ Amat, const unsigned short* __restrict__ u2bf,
    unsigned short* __restrict__ hbf,
    const unsigned short* __restrict__ xbf, const unsigned short* __restrict__ WgT,
    const float* __restrict__ b_gate, unsigned short* __restrict__ gbf,
    const unsigned short* __restrict__ WDT, const float* __restrict__ bD,
    float* __restrict__ big,
    const unsigned short* __restrict__ Cbf, unsigned short* __restrict__ ysbf,
    const unsigned short* __restrict__ WoT, const float* __restrict__ b_out,
    const float* __restrict__ x, float* __restrict__ outp,
    unsigned* __restrict__ flags,
    int M, int DM, int DS)
{
    __shared__ __align__(16) unsigned char LDSM[131072];
    const int tid = threadIdx.x;
    const unsigned bid = blockIdx.x;
    unsigned* scan_prog = flags + 0;
    unsigned* gate_done = flags + 1;
    unsigned* wd_done   = flags + 2;
    unsigned* cg_done   = flags + 16;   // [128]

    if (bid == 0) {
        scan_body(LDSM, tid, Amat, u2bf, hbf, scan_prog);
        return;
    }
    const bool act = tid < 256;
    const int t2 = tid & 255;
    if (bid <= 1024) {
        const int t = bid - 1;
        gemm_tile<E_SIGBF>(act, LDSM, t & 7, t >> 3, t2, xbf, WgT, b_gate,
                           nullptr, nullptr, nullptr, gbf, M, DM, DM);
        asm volatile("s_waitcnt vmcnt(0)" ::: "memory");
        __syncthreads();
        if (tid == 0) { __threadfence(); atomicAdd(gate_done, 1u); }
    } else if (bid <= 2048) {
        const int t = bid - 1025;
        gemm_tile<E_BIASF32>(act, LDSM, t & 7, t >> 3, t2, xbf, WDT, bD,
                             nullptr, nullptr, nullptr, big, M, DM, DM);
        asm volatile("s_waitcnt vmcnt(0)" ::: "memory");
        __syncthreads();
        if (tid == 0) { __threadfence(); atomicAdd(wd_done, 1u); }
    } else {
        const int t = bid - 2049;          // 0..2047
        const int tg = t >> 7;             // row-group 0..15
        const int r128 = t & 127;
        if (r128 < 64) {
            const int b = r128 >> 3, bx = r128 & 7;
            const int by = b * 16 + tg;
            wait_ge(gate_done, 1024, tid);
            wait_ge(wd_done, 1024, tid);
            wait_ge(scan_prog, (unsigned)(tg + 1), tid);
            gemm_tile<E_GATE>(act, LDSM, bx, by, t2, hbf, Cbf, nullptr, x,
                              big, gbf, ysbf, M, DM, DS);
            asm volatile("s_waitcnt vmcnt(0)" ::: "memory");
            __syncthreads();
            if (tid == 0) { __threadfence(); atomicAdd(&cg_done[by], 1u); }
        } else {
            const int o = r128 - 64;
            const int b = o >> 3, bx = o & 7;
            const int by = b * 16 + tg;
            wait_ge(&cg_done[by], 8, tid);
            gemm_tile<E_BIASRES>(act, LDSM, bx, by, t2, ysbf, WoT, b_out, x,
                                 nullptr, nullptr, outp, M, DM, DM);
        }
    }
}

extern "C" void kernel_launch(void* const* d_in, const int* in_sizes, int n_in,
                              void* d_out, int out_size, void* d_ws, size_t ws_size,
                              hipStream_t stream)
{
    const float* x      = (const float*)d_in[0];
    const float* W_in   = (const float*)d_in[1];
    const float* b_in   = (const float*)d_in[2];
    const float* W_gate = (const float*)d_in[3];
    const float* b_gate = (const float*)d_in[4];
    const float* Amat   = (const float*)d_in[5];
    const float* Bm     = (const float*)d_in[6];
    const float* Cm     = (const float*)d_in[7];
    const float* Dm     = (const float*)d_in[8];
    const float* W_out  = (const float*)d_in[9];
    const float* b_out  = (const float*)d_in[10];

    const int T = 2048, DM = 1024, DS = 256;
    const int M = 8 * T;  // 16384
    const size_t MB = 1024 * 1024;
    char* ws = (char*)d_ws;

    unsigned short* xbf   = (unsigned short*)(ws);
    unsigned short* ysbf  = xbf;
    unsigned short* Winbf = (unsigned short*)(ws + 32 * MB);
    unsigned short* Dbf   = (unsigned short*)(ws + 33 * MB);
    unsigned short* W2T   = (unsigned short*)(ws + 34 * MB);
    unsigned short* WDT   = (unsigned short*)(ws + 35 * MB);
    float*          b2    = (float*)(ws + 38 * MB);
    float*          bD    = (float*)(ws + 38 * MB + 65536);
    unsigned*       flags = (unsigned*)(ws + 39 * MB);
    unsigned short* u2    = (unsigned short*)(ws + 40 * MB);
    unsigned short* h     = (unsigned short*)(ws + 56 * MB);
    unsigned short* BmT   = (unsigned short*)(ws + 64 * MB);
    unsigned short* WgT   = (unsigned short*)(ws + 65 * MB);
    unsigned short* WoT   = (unsigned short*)(ws + 67 * MB);
    unsigned short* Cbf   = (unsigned short*)(ws + 69 * MB);
    float*          big   = (float*)(ws + 70 * MB);
    unsigned short* gbf   = (unsigned short*)(ws + 134 * MB);

    hipMemsetAsync(flags, 0, 4096, stream);

    prep_all<<<10693, 256, 0, stream>>>(x, xbf, W_in, Winbf, Dm, Dbf, Bm, BmT,
                                        W_gate, WgT, W_out, WoT, Cm, Cbf,
                                        b_in, b2, bD);

    gemm_mfma<E_CVTBF><<<dim3(DM / 128, DS / 128), 256, 0, stream>>>(
        BmT, Winbf, nullptr, nullptr, nullptr, nullptr, W2T, DS, DM, DS);
    gemm_mfma<E_CVTBF><<<dim3(DM / 128, DM / 128), 256, 0, stream>>>(
        Dbf, Winbf, nullptr, nullptr, nullptr, nullptr, WDT, DM, DM, DS);

    gemm_mfma<E_BIASBF><<<dim3(DS / 128, M / 128), 256, 0, stream>>>(
        xbf, W2T, b2, nullptr, nullptr, nullptr, u2, M, DS, DM);

    fused_scan<<<4097, 512, 0, stream>>>(
        Amat, u2, h, xbf, WgT, b_gate, gbf, WDT, bD, big,
        Cbf, ysbf, WoT, b_out, x, (float*)d_out, flags, M, DM, DS);
}

// Round 16
// 1439.516 us; speedup vs baseline: 1.1382x; 1.1382x over previous
//
#include <hip/hip_runtime.h>
#include <math.h>

// MambaBlock: B=8, T=2048, D_MODEL=1024, D_STATE=256.
// R16 = R14 exact revert (best-known: 1443 us). R15's depth-2 MFMA chains
// regressed -13% (as did R12's bundle); R14's step structure is the floor:
// ~620 cy/step matrix-pipe + ~900 cy sync/latency tail, 7 attacks failed.
// All scan-independent GEMMs hidden under the scan via role-blocks + flags.

enum { E_NONE = 0, E_BIASBF = 1, E_SIGBF = 2, E_GATE = 3, E_BIASRES = 4,
       E_CVTBF = 5, E_BIASF32 = 6 };

typedef __attribute__((ext_vector_type(8))) short bf16x8;
typedef __attribute__((ext_vector_type(4))) float f32x4;

static __device__ inline unsigned short f2bf(float f) {
    unsigned u = __builtin_bit_cast(unsigned, f);
    unsigned r = (u + 0x7fff + ((u >> 16) & 1)) >> 16;
    return (unsigned short)r;
}
static __device__ inline unsigned pack2(float a, float b) {
    return (unsigned)f2bf(a) | ((unsigned)f2bf(b) << 16);
}
static __device__ inline float bflo(unsigned u) {
    return __builtin_bit_cast(float, u << 16);
}
static __device__ inline float bfhi(unsigned u) {
    return __builtin_bit_cast(float, u & 0xffff0000u);
}
static __device__ inline float tanh_fast(float x) {
    float e = __builtin_amdgcn_exp2f(x * 2.8853900817779268f);
    float t = __builtin_amdgcn_rcpf(e + 1.0f);
    return fmaf(-2.0f, t, 1.0f);
}

// ---------------- flag helpers (device-scope release/acquire) ----------------
static __device__ __forceinline__ void wait_ge(unsigned* p, unsigned tgt, int tid) {
    if (tid == 0) {
        while (atomicAdd(p, 0u) < tgt) __builtin_amdgcn_s_sleep(2);
        __threadfence();   // acquire: invalidate local caches
    }
    __syncthreads();
}

// ---------------- role bodies ----------------
static __device__ __forceinline__ void cvt_body(
    const float* __restrict__ in, unsigned short* __restrict__ out, int i, int n8)
{
    if (i >= n8) return;
    float4 a = ((const float4*)in)[i * 2];
    float4 b = ((const float4*)in)[i * 2 + 1];
    uint4 o;
    o.x = pack2(a.x, a.y); o.y = pack2(a.z, a.w);
    o.z = pack2(b.x, b.y); o.w = pack2(b.z, b.w);
    ((uint4*)out)[i] = o;
}

static __device__ __forceinline__ void transpose_tile(
    bool act, unsigned char* LdsB, int bxi, int byi, int t2,
    const float* __restrict__ in, unsigned short* __restrict__ out, int R, int C)
{
    float* tile = (float*)LdsB;  // [32][33]
    const int bx = bxi * 32, by = byi * 32;
    const int tx = t2 & 31, ty = t2 >> 5;  // ty 0..7
    if (act) {
#pragma unroll
        for (int i = 0; i < 32; i += 8)
            tile[(ty + i) * 33 + tx] = in[(size_t)(by + ty + i) * C + bx + tx];
    }
    __syncthreads();
    if (act) {
#pragma unroll
        for (int i = 0; i < 32; i += 8)
            out[(size_t)(bx + ty + i) * R + by + tx] = f2bf(tile[tx * 33 + ty + i]);
    }
}

// ---------------- combined prepass (role blocks) ----------------
// 0..8191 xcvt | +128 Win cvt | +128 D cvt | +64 BmT | +1024 WgT |
// +1024 WoT | +128 C cvt | +1 b2 | +4 bD     (grid 10693)
__global__ __launch_bounds__(256) void prep_all(
    const float* __restrict__ x, unsigned short* __restrict__ xbf,
    const float* __restrict__ W_in, unsigned short* __restrict__ Winbf,
    const float* __restrict__ Dm, unsigned short* __restrict__ Dbf,
    const float* __restrict__ Bm, unsigned short* __restrict__ BmT,
    const float* __restrict__ W_gate, unsigned short* __restrict__ WgT,
    const float* __restrict__ W_out, unsigned short* __restrict__ WoT,
    const float* __restrict__ Cm, unsigned short* __restrict__ Cbf,
    const float* __restrict__ b_in, float* __restrict__ b2, float* __restrict__ bD)
{
    __shared__ __align__(16) unsigned char Lds[32 * 33 * 4];
    const unsigned bid = blockIdx.x;
    const int tid = threadIdx.x;
    if (bid < 8192) {
        cvt_body(x, xbf, bid * 256 + tid, 16384 * 1024 / 8);
    } else if (bid < 8320) {
        cvt_body(W_in, Winbf, (bid - 8192) * 256 + tid, 1024 * 256 / 8);
    } else if (bid < 8448) {
        cvt_body(Dm, Dbf, (bid - 8320) * 256 + tid, 1024 * 256 / 8);
    } else if (bid < 8512) {
        const int t = bid - 8448;
        transpose_tile(true, Lds, t & 7, t >> 3, tid, Bm, BmT, 256, 256);
    } else if (bid < 9536) {
        const int t = bid - 8512;
        transpose_tile(true, Lds, t & 31, t >> 5, tid, W_gate, WgT, 1024, 1024);
    } else if (bid < 10560) {
        const int t = bid - 9536;
        transpose_tile(true, Lds, t & 31, t >> 5, tid, W_out, WoT, 1024, 1024);
    } else if (bid < 10688) {
        cvt_body(Cm, Cbf, (bid - 10560) * 256 + tid, 1024 * 256 / 8);
    } else if (bid == 10688) {
        float s = 0.f;
        for (int k = 0; k < 256; ++k) s = fmaf(b_in[k], Bm[k * 256 + tid], s);
        b2[tid] = s;
    } else {
        const int n = (bid - 10689) * 256 + tid;
        float s = 0.f;
        for (int k = 0; k < 256; ++k) s = fmaf(b_in[k], Dm[n * 256 + k], s);
        bD[n] = s;
    }
}

// ---------------- bf16 MFMA GEMM tile: C[M,N] = A[M,K] * B[N,K]^T ----------
template <int EPI>
static __device__ __forceinline__ void gemm_tile(
    bool act, unsigned char* Lds, int bx, int by, int tid,
    const unsigned short* __restrict__ Ag,  // [M,K] bf16
    const unsigned short* __restrict__ Bg,  // [N,K] bf16
    const float* __restrict__ bias, const float* __restrict__ res,
    const float* __restrict__ acc_src, const unsigned short* __restrict__ g8,
    void* Cg, int M, int N, int K)
{
    const int w = (tid >> 6) & 3, l = tid & 63;
    const int r = l & 15, g = l >> 4;
    const int m0 = by * 128, n0 = bx * 128;

    const unsigned char* agp[4];
    const unsigned char* bgp[4];
#pragma unroll
    for (int j = 0; j < 4; ++j) {
        const int c = w * 256 + j * 64 + l;
        const int row = c >> 3;
        const unsigned offp = ((unsigned)(c & 7) * 16u) ^ ((unsigned)(row & 7) * 16u);
        agp[j] = (const unsigned char*)Ag + ((size_t)(m0 + row) * K) * 2 + offp;
        bgp[j] = (const unsigned char*)Bg + ((size_t)(n0 + row) * K) * 2 + offp;
    }

#define GSTAGE(BUF)                                                           \
    {                                                                         \
      _Pragma("unroll")                                                       \
      for (int j = 0; j < 4; ++j) {                                           \
        __builtin_amdgcn_global_load_lds(                                     \
            (const __attribute__((address_space(1))) unsigned*)(agp[j]),      \
            (__attribute__((address_space(3))) unsigned*)(Lds + (BUF) * 32768 + w * 4096 + j * 1024), \
            16, 0, 0);                                                        \
        __builtin_amdgcn_global_load_lds(                                     \
            (const __attribute__((address_space(1))) unsigned*)(bgp[j]),      \
            (__attribute__((address_space(3))) unsigned*)(Lds + (BUF) * 32768 + 16384 + w * 4096 + j * 1024), \
            16, 0, 0);                                                        \
        agp[j] += 128; bgp[j] += 128;                                         \
      }                                                                       \
    }

    f32x4 acc[2][8];
#pragma unroll
    for (int mt = 0; mt < 2; ++mt)
#pragma unroll
        for (int nt = 0; nt < 8; ++nt) acc[mt][nt] = (f32x4){0.f, 0.f, 0.f, 0.f};

    const int nk = K >> 6;
    if (act) GSTAGE(0)
    __syncthreads();
    for (int t = 0; t < nk; ++t) {
        const int buf = t & 1;
        if (act) {
            if (t + 1 < nk) GSTAGE(buf ^ 1)
            bf16x8 af[2][2], bfr[8][2];
#pragma unroll
            for (int s = 0; s < 2; ++s) {
#pragma unroll
                for (int mt = 0; mt < 2; ++mt) {
                    const int row = w * 32 + mt * 16 + r;
                    af[mt][s] = *(const bf16x8*)(Lds + buf * 32768 + row * 128 +
                        ((s * 64 + 16 * g) ^ (16 * (row & 7))));
                }
#pragma unroll
                for (int nt = 0; nt < 8; ++nt) {
                    const int row = nt * 16 + r;
                    bfr[nt][s] = *(const bf16x8*)(Lds + buf * 32768 + 16384 + row * 128 +
                        ((s * 64 + 16 * g) ^ (16 * (row & 7))));
                }
            }
#pragma unroll
            for (int s = 0; s < 2; ++s)
#pragma unroll
                for (int mt = 0; mt < 2; ++mt)
#pragma unroll
                    for (int nt = 0; nt < 8; ++nt)
                        acc[mt][nt] = __builtin_amdgcn_mfma_f32_16x16x32_bf16(
                            af[mt][s], bfr[nt][s], acc[mt][nt], 0, 0, 0);
        }
        __syncthreads();
    }
#undef GSTAGE

    if (act) {
#pragma unroll
        for (int mt = 0; mt < 2; ++mt)
#pragma unroll
            for (int nt = 0; nt < 8; ++nt) {
                const int n = n0 + nt * 16 + r;
                float bv = 0.f;
                if (EPI == E_BIASBF || EPI == E_SIGBF || EPI == E_BIASRES ||
                    EPI == E_BIASF32) bv = bias[n];
#pragma unroll
                for (int q = 0; q < 4; ++q) {
                    const int m = m0 + w * 32 + mt * 16 + g * 4 + q;
                    const size_t idx = (size_t)m * N + n;
                    float v = acc[mt][nt][q] + bv;
                    if (EPI == E_SIGBF) v = 1.f / (1.f + expf(-v));
                    if (EPI == E_BIASRES) v += res[idx];
                    if (EPI == E_GATE) {
                        v += acc_src[idx];
                        const float gg = bflo((unsigned)g8[idx]);
                        v = gg * v + (1.f - gg) * res[idx];
                    }
                    if (EPI == E_BIASBF || EPI == E_SIGBF || EPI == E_CVTBF ||
                        EPI == E_GATE)
                        ((unsigned short*)Cg)[idx] = f2bf(v);
                    else
                        ((float*)Cg)[idx] = v;
                }
            }
    }
}

template <int EPI>
__global__ __launch_bounds__(256) void gemm_mfma(
    const unsigned short* __restrict__ Ag, const unsigned short* __restrict__ Bg,
    const float* __restrict__ bias, const float* __restrict__ res,
    const float* __restrict__ acc_src, const unsigned short* __restrict__ g8,
    void* Cg, int M, int N, int K)
{
    __shared__ __align__(16) unsigned char Lds[65536];
    gemm_tile<EPI>(true, Lds, blockIdx.x, blockIdx.y, threadIdx.x,
                   Ag, Bg, bias, res, acc_src, g8, Cg, M, N, K);
}

// ---------------- 8-wave MFMA scan body (R11 step, + progress publish) -----
static __device__ __forceinline__ void scan_body(
    unsigned char* LDSM, int tid,
    const float* __restrict__ Amat, const unsigned short* __restrict__ u2bf,
    unsigned short* __restrict__ hbf, unsigned* __restrict__ scan_prog)
{
    constexpr int T = 2048;
    constexpr int NCH = T / 8;  // 256 chunks
    unsigned char* Hb = LDSM;              // ring [16][4096]
    unsigned char* Ub = LDSM + 65536;      // [2 buf][8 steps][8 b][512 B]

    const int w = tid >> 6, l = tid & 63;
    const int r = l & 15, g = l >> 4, r8 = r & 7;
    const bool hi = (r & 8) != 0;
    const int m0 = w * 32;

    ((unsigned*)Hb)[tid] = 0u;
    ((unsigned*)Hb)[tid + 512] = 0u;

    bf16x8 af[2][8];
#pragma unroll
    for (int mt = 0; mt < 2; ++mt) {
        const int m = m0 + mt * 16 + r;
#pragma unroll
        for (int kt = 0; kt < 8; ++kt) {
            unsigned wd[4];
#pragma unroll
            for (int jw = 0; jw < 4; ++jw) {
                const int k = kt * 32 + g * 8 + jw * 2;
                wd[jw] = pack2(Amat[(size_t)k * 256 + m],
                               Amat[(size_t)(k + 1) * 256 + m]);
            }
            af[mt][kt] = __builtin_bit_cast(bf16x8, *(uint4*)wd);
        }
    }

    unsigned ubase[2], woff[2];
#pragma unroll
    for (int mt = 0; mt < 2; ++mt) {
        const int s0 = m0 + mt * 16 + g * 4;
        const int s = s0 + (hi ? 2 : 0);
        ubase[mt] = (unsigned)(r8 * 512 + (((s >> 3) ^ r8) * 16) + (s & 7) * 2);
        woff[mt] = (unsigned)((((s0 >> 5) * 32 + ((s0 >> 3) & 3) * 8 + r8) * 16)
                              + ((s0 & 7) + (hi ? 2 : 0)) * 2);
    }
    const unsigned rbase = (unsigned)((g * 8 + r8) * 16);

    int sg_i[4], sg_b[4], sg_kg[4];
#pragma unroll
    for (int j = 0; j < 4; ++j) {
        const int d = j * 512 + tid;
        sg_i[j] = d >> 8;
        sg_b[j] = (d >> 5) & 7;
        sg_kg[j] = (d & 31) ^ sg_b[j];
    }

#pragma unroll
    for (int c0 = 0; c0 < 2; ++c0)
#pragma unroll
        for (int j = 0; j < 4; ++j) {
            const size_t srcb = ((size_t)(sg_b[j] * T + c0 * 8 + sg_i[j]) * 512)
                              + (unsigned)(sg_kg[j] * 16);
            __builtin_amdgcn_global_load_lds(
                (const __attribute__((address_space(1))) unsigned*)(
                    (const unsigned char*)u2bf + srcb),
                (__attribute__((address_space(3))) unsigned*)(
                    Ub + c0 * 32768 + (j * 512 + tid) * 16), 16, 0, 0);
        }
    asm volatile("s_waitcnt vmcnt(0) lgkmcnt(0)" ::: "memory");
    __builtin_amdgcn_sched_barrier(0);
    __builtin_amdgcn_s_barrier();
    __builtin_amdgcn_sched_barrier(0);

#define SCAN_STEP(I)                                                          \
  {                                                                           \
    const unsigned sr = ((unsigned)(t0 + (I)) & 15u) * 4096u;                 \
    const unsigned sw = ((unsigned)(t0 + (I) + 1) & 15u) * 4096u;             \
    bf16x8 hf[8];                                                             \
    _Pragma("unroll")                                                         \
    for (int kt = 0; kt < 8; ++kt)                                            \
      hf[kt] = *(const bf16x8*)(Hb + sr + rbase + (unsigned)(kt * 512));      \
    unsigned uv[2];                                                           \
    _Pragma("unroll")                                                         \
    for (int mt = 0; mt < 2; ++mt)                                            \
      uv[mt] = *(const unsigned*)(Uc + (unsigned)(I) * 4096u + ubase[mt]);    \
    f32x4 p0[2], p1[2];                                                       \
    _Pragma("unroll")                                                         \
    for (int mt = 0; mt < 2; ++mt) {                                          \
      p0[mt] = (f32x4){0.f, 0.f, 0.f, 0.f};                                   \
      p1[mt] = (f32x4){0.f, 0.f, 0.f, 0.f};                                   \
    }                                                                         \
    _Pragma("unroll")                                                         \
    for (int kt = 0; kt < 4; ++kt) {                                          \
      _Pragma("unroll")                                                       \
      for (int mt = 0; mt < 2; ++mt) {                                        \
        p0[mt] = __builtin_amdgcn_mfma_f32_16x16x32_bf16(af[mt][kt], hf[kt],  \
                                                         p0[mt], 0, 0, 0);    \
        p1[mt] = __builtin_amdgcn_mfma_f32_16x16x32_bf16(                     \
            af[mt][kt + 4], hf[kt + 4], p1[mt], 0, 0, 0);                     \
      }                                                                       \
    }                                                                         \
    _Pragma("unroll")                                                         \
    for (int mt = 0; mt < 2; ++mt) {                                          \
      const float slo = hi ? (p0[mt][2] + p1[mt][2]) : (p0[mt][0] + p1[mt][0]);\
      const float shi = hi ? (p0[mt][3] + p1[mt][3]) : (p0[mt][1] + p1[mt][1]);\
      const float h0 = tanh_fast(slo + bflo(uv[mt]));                         \
      const float h1 = tanh_fast(shi + bfhi(uv[mt]));                         \
      unsigned pk;                                                            \
      asm("v_cvt_pk_bf16_f32 %0, %1, %2" : "=v"(pk) : "v"(h0), "v"(h1));      \
      *(unsigned*)(Hb + sw + woff[mt]) = pk;                                  \
    }                                                                         \
    asm volatile("s_waitcnt lgkmcnt(0)" ::: "memory");                        \
    __builtin_amdgcn_sched_barrier(0);                                        \
    __builtin_amdgcn_s_barrier();                                             \
    __builtin_amdgcn_sched_barrier(0);                                        \
  }

    for (int chunk = 0; chunk < NCH; ++chunk) {
        const int t0 = chunk * 8;
        const unsigned char* Uc = Ub + ((unsigned)(chunk & 1) << 15);

        SCAN_STEP(0)
        SCAN_STEP(1)
        SCAN_STEP(2)
        SCAN_STEP(3)
        SCAN_STEP(4)
        SCAN_STEP(5)
        SCAN_STEP(6)
        SCAN_STEP(7)

        {
#pragma unroll
            for (int j = 0; j < 4; ++j) {
                const int p = j * 512 + tid;
                const int di = p >> 8, wp = p & 255;
                const int kt_ = wp >> 5, sl_ = wp & 31;
                const unsigned slot = (unsigned)((t0 + 1 + di) & 15) * 4096u;
                uint4 dat = *(const uint4*)(Hb + slot + (unsigned)wp * 16u);
                const size_t off = ((size_t)((sl_ & 7) * T + t0 + di) * 256 +
                                    kt_ * 32 + (sl_ >> 3) * 8);
                *(uint4*)(hbf + off) = dat;
            }
            if (chunk + 2 < NCH) {
                const unsigned nb = (unsigned)(chunk & 1) << 15;
#pragma unroll
                for (int j = 0; j < 4; ++j) {
                    const size_t srcb =
                        ((size_t)(sg_b[j] * T + t0 + 16 + sg_i[j]) * 512)
                        + (unsigned)(sg_kg[j] * 16);
                    __builtin_amdgcn_global_load_lds(
                        (const __attribute__((address_space(1))) unsigned*)(
                            (const unsigned char*)u2bf + srcb),
                        (__attribute__((address_space(3))) unsigned*)(
                            Ub + nb + (j * 512 + tid) * 16), 16, 0, 0);
                }
                // FIFO: this chunk's 4 dump stores retire before the 8 new
                // staging loads -> vmcnt(8) guarantees h visible in L2.
                asm volatile("s_waitcnt vmcnt(8) lgkmcnt(0)" ::: "memory");
            } else {
                asm volatile("s_waitcnt vmcnt(0) lgkmcnt(0)" ::: "memory");
            }
            __builtin_amdgcn_sched_barrier(0);
            __builtin_amdgcn_s_barrier();
            __builtin_amdgcn_sched_barrier(0);
            // publish every 16 chunks (128 timesteps) — release fence + inc
            if ((chunk & 15) == 15 && tid == 0) {
                __threadfence();
                atomicAdd(scan_prog, 1u);
            }
        }
    }
#undef SCAN_STEP
}

// ---------------- fused kernel ----------------
// bid 0: scan. 1..1024: gate GEMM (-> gate_done). 1025..2048: WD GEMM
// (-> wd_done). 2049..4096: per row-group tg (0..15): 64 C-gate tiles
// (wait gate+WD+scan_prog>=tg+1, -> cg_done[by]) then 64 out tiles
// (wait cg_done[by]==8). All waits point to earlier block IDs.
__global__ __launch_bounds__(512, 1) void fused_scan(
    const float* __restrict__ Amat, const unsigned short* __restrict__ u2bf,
    unsigned short* __restrict__ hbf,
    const unsigned short* __restrict__ xbf, const unsigned short* __restrict__ WgT,
    const float* __restrict__ b_gate, unsigned short* __restrict__ gbf,
    const unsigned short* __restrict__ WDT, const float* __restrict__ bD,
    float* __restrict__ big,
    const unsigned short* __restrict__ Cbf, unsigned short* __restrict__ ysbf,
    const unsigned short* __restrict__ WoT, const float* __restrict__ b_out,
    const float* __restrict__ x, float* __restrict__ outp,
    unsigned* __restrict__ flags,
    int M, int DM, int DS)
{
    __shared__ __align__(16) unsigned char LDSM[131072];
    const int tid = threadIdx.x;
    const unsigned bid = blockIdx.x;
    unsigned* scan_prog = flags + 0;
    unsigned* gate_done = flags + 1;
    unsigned* wd_done   = flags + 2;
    unsigned* cg_done   = flags + 16;   // [128]

    if (bid == 0) {
        scan_body(LDSM, tid, Amat, u2bf, hbf, scan_prog);
        return;
    }
    const bool act = tid < 256;
    const int t2 = tid & 255;
    if (bid <= 1024) {
        const int t = bid - 1;
        gemm_tile<E_SIGBF>(act, LDSM, t & 7, t >> 3, t2, xbf, WgT, b_gate,
                           nullptr, nullptr, nullptr, gbf, M, DM, DM);
        asm volatile("s_waitcnt vmcnt(0)" ::: "memory");
        __syncthreads();
        if (tid == 0) { __threadfence(); atomicAdd(gate_done, 1u); }
    } else if (bid <= 2048) {
        const int t = bid - 1025;
        gemm_tile<E_BIASF32>(act, LDSM, t & 7, t >> 3, t2, xbf, WDT, bD,
                             nullptr, nullptr, nullptr, big, M, DM, DM);
        asm volatile("s_waitcnt vmcnt(0)" ::: "memory");
        __syncthreads();
        if (tid == 0) { __threadfence(); atomicAdd(wd_done, 1u); }
    } else {
        const int t = bid - 2049;          // 0..2047
        const int tg = t >> 7;             // row-group 0..15
        const int r128 = t & 127;
        if (r128 < 64) {
            // C-gate tile: ysbf = bf16(g*(h@C^T + big) + (1-g)*x)
            const int b = r128 >> 3, bx = r128 & 7;
            const int by = b * 16 + tg;
            wait_ge(gate_done, 1024, tid);
            wait_ge(wd_done, 1024, tid);
            wait_ge(scan_prog, (unsigned)(tg + 1), tid);
            gemm_tile<E_GATE>(act, LDSM, bx, by, t2, hbf, Cbf, nullptr, x,
                              big, gbf, ysbf, M, DM, DS);
            asm volatile("s_waitcnt vmcnt(0)" ::: "memory");
            __syncthreads();
            if (tid == 0) { __threadfence(); atomicAdd(&cg_done[by], 1u); }
        } else {
            // out tile: outp = ysbf @ W_out + b_out + x
            const int o = r128 - 64;
            const int b = o >> 3, bx = o & 7;
            const int by = b * 16 + tg;
            wait_ge(&cg_done[by], 8, tid);
            gemm_tile<E_BIASRES>(act, LDSM, bx, by, t2, ysbf, WoT, b_out, x,
                                 nullptr, nullptr, outp, M, DM, DM);
        }
    }
}

extern "C" void kernel_launch(void* const* d_in, const int* in_sizes, int n_in,
                              void* d_out, int out_size, void* d_ws, size_t ws_size,
                              hipStream_t stream)
{
    const float* x      = (const float*)d_in[0];
    const float* W_in   = (const float*)d_in[1];
    const float* b_in   = (const float*)d_in[2];
    const float* W_gate = (const float*)d_in[3];
    const float* b_gate = (const float*)d_in[4];
    const float* Amat   = (const float*)d_in[5];
    const float* Bm     = (const float*)d_in[6];
    const float* Cm     = (const float*)d_in[7];
    const float* Dm     = (const float*)d_in[8];
    const float* W_out  = (const float*)d_in[9];
    const float* b_out  = (const float*)d_in[10];

    const int T = 2048, DM = 1024, DS = 256;
    const int M = 8 * T;  // 16384
    const size_t MB = 1024 * 1024;
    char* ws = (char*)d_ws;

    unsigned short* xbf   = (unsigned short*)(ws);            // 32 MB
    unsigned short* ysbf  = xbf;                              // reuse (flag-safe)
    unsigned short* Winbf = (unsigned short*)(ws + 32 * MB);
    unsigned short* Dbf   = (unsigned short*)(ws + 33 * MB);
    unsigned short* W2T   = (unsigned short*)(ws + 34 * MB);  // [256,1024]
    unsigned short* WDT   = (unsigned short*)(ws + 35 * MB);  // [1024,1024]
    float*          b2    = (float*)(ws + 38 * MB);
    float*          bD    = (float*)(ws + 38 * MB + 65536);
    unsigned*       flags = (unsigned*)(ws + 39 * MB);        // 4 KB
    unsigned short* u2    = (unsigned short*)(ws + 40 * MB);  // bf16 [16384,256]
    unsigned short* h     = (unsigned short*)(ws + 56 * MB);  // bf16 [16384,256]
    unsigned short* BmT   = (unsigned short*)(ws + 64 * MB);
    unsigned short* WgT   = (unsigned short*)(ws + 65 * MB);
    unsigned short* WoT   = (unsigned short*)(ws + 67 * MB);
    unsigned short* Cbf   = (unsigned short*)(ws + 69 * MB);
    float*          big   = (float*)(ws + 70 * MB);           // 64 MB f32
    unsigned short* gbf   = (unsigned short*)(ws + 134 * MB); // 32 MB

    // reset flags (deterministic across replays)
    hipMemsetAsync(flags, 0, 4096, stream);

    // combined prepass
    prep_all<<<10693, 256, 0, stream>>>(x, xbf, W_in, Winbf, Dm, Dbf, Bm, BmT,
                                        W_gate, WgT, W_out, WoT, Cm, Cbf,
                                        b_in, b2, bD);

    // W2T = (W_in @ Bm)^T ; WDT = (W_in @ D^T)^T
    gemm_mfma<E_CVTBF><<<dim3(DM / 128, DS / 128), 256, 0, stream>>>(
        BmT, Winbf, nullptr, nullptr, nullptr, nullptr, W2T, DS, DM, DS);
    gemm_mfma<E_CVTBF><<<dim3(DM / 128, DM / 128), 256, 0, stream>>>(
        Dbf, Winbf, nullptr, nullptr, nullptr, nullptr, WDT, DM, DM, DS);

    // u2 = bf16(x @ W2 + b2)
    gemm_mfma<E_BIASBF><<<dim3(DS / 128, M / 128), 256, 0, stream>>>(
        xbf, W2T, b2, nullptr, nullptr, nullptr, u2, M, DS, DM);

    // fused: scan + gate + WD + pipelined C-gate + pipelined out
    fused_scan<<<4097, 512, 0, stream>>>(
        Amat, u2, h, xbf, WgT, b_gate, gbf, WDT, bD, big,
        Cbf, ysbf, WoT, b_out, x, (float*)d_out, flags, M, DM, DS);
}